// Round 1
// baseline (192.006 us; speedup 1.0000x reference)
//
#include <hip/hip_runtime.h>
#include <hip/hip_bf16.h>

// SparseMHA, fixed out-degree CSR graph attention. fp32 in/out.
// r9 -> r10:
//  * qkv: the 6 global_load_lds phases were each drained by __syncthreads
//    (s_waitcnt vmcnt(0)) with ~1 block/CU -> serialized DMA latency 6x per
//    block. Now double-buffered LDS (2x32KB) + counted vmcnt(8) + raw
//    s_barrier: phase p+1's loads fly under phase p's MFMAs. Allowance is a
//    conservative 8 everywhere (0 at tail) so correctness never depends on the
//    epilogue's predicated-store count. Math/layout identical to r9.
//  * attn: latency-bound random gather (MfmaUtil 2%, VALU 39%, 48% app. BW,
//    FETCH 179MB vs 42MB ideal -> L3-served re-reads). 2 rows per wave ->
//    ~2x outstanding loads per wave, halves per-row fixed cost.

typedef unsigned short ushort_t;
typedef unsigned int uint32;
typedef short short8 __attribute__((ext_vector_type(8)));
typedef short short4v __attribute__((ext_vector_type(4)));
typedef float f32x4 __attribute__((ext_vector_type(4)));

#define HID 128
#define DEG 16
#define OSTRIDE_LDS 132   // ushort row stride in LDS repack (bank-conflict-free)

__device__ __forceinline__ float bf2f(ushort_t u) {
  uint32 x = ((uint32)u) << 16;
  return __builtin_bit_cast(float, x);
}
__device__ __forceinline__ ushort_t f2bf(float f) {
  uint32 u = __builtin_bit_cast(uint32, f);
  u += 0x7fffu + ((u >> 16) & 1u);   // RNE
  return (ushort_t)(u >> 16);
}

// Packed split of 2 fp32 -> packed bf16 hi pair + lo pair (RNE, v_cvt_pk path).
__device__ __forceinline__ void split2(float x, float y, uint32& hi, uint32& lo) {
  __hip_bfloat162 h2 = __float22bfloat162_rn(float2{x, y});
  __builtin_memcpy(&hi, &h2, 4);
  float hx = __builtin_bit_cast(float, hi << 16);
  float hy = __builtin_bit_cast(float, hi & 0xffff0000u);
  __hip_bfloat162 l2 = __float22bfloat162_rn(float2{x - hx, y - hy});
  __builtin_memcpy(&lo, &l2, 4);
}

__device__ __forceinline__ void split8v(float4 a, float4 b, short8& hi, short8& lo) {
  uint32* hu = (uint32*)&hi;
  uint32* lu = (uint32*)&lo;
  split2(a.x, a.y, hu[0], lu[0]);
  split2(a.z, a.w, hu[1], lu[1]);
  split2(b.x, b.y, hu[2], lu[2]);
  split2(b.z, b.w, hu[3], lu[3]);
}

__device__ __forceinline__ void split8p(const float* __restrict__ p, short8& hi, short8& lo) {
  float4 a = *(const float4*)p;
  float4 b = *(const float4*)(p + 4);
  split8v(a, b, hi, lo);
}

// ---------------- Phase 0: pre-split Wq|Wk|Wv into bf16 hi/lo ----------------
__global__ __launch_bounds__(256) void prep_kernel(
    const float* __restrict__ Wq, const float* __restrict__ Wk,
    const float* __restrict__ Wv,
    ushort_t* __restrict__ whi, ushort_t* __restrict__ wlo) {
  const int idx8 = (blockIdx.x * 256 + threadIdx.x) * 8;   // [0, 49152)
  const float* W = (idx8 < 16384) ? Wq : (idx8 < 32768) ? Wk : Wv;
  const int off = idx8 & 16383;
  short8 hi, lo;
  split8p(W + off, hi, lo);
  *(short8*)(whi + idx8) = hi;
  *(short8*)(wlo + idx8) = lo;
}

// ---------------- Phase 1: fused Q+K+V projection, pipelined ----------------
#define WAITV(n) asm volatile("s_waitcnt vmcnt(" #n ")" ::: "memory")
#define BARRIER() __builtin_amdgcn_s_barrier()
#define MEMPIN() asm volatile("" ::: "memory")

// B fragment slot j = t*4+kt (1KB each): lane l holds bytes j*1024 + l*16.
__device__ __forceinline__ void stage_w(const ushort_t* __restrict__ W,
                                        char* lb, int wave, int l) {
  const int lm = l & 15, lq = l >> 4;
#pragma unroll
  for (int jj = 0; jj < 8; jj++) {
    const int j = wave * 8 + jj, t = j >> 2, kt = j & 3;
    const ushort_t* gp = W + (t * 16 + lm) * HID + kt * 32 + lq * 8;
    __builtin_amdgcn_global_load_lds(
        (const __attribute__((address_space(1))) void*)gp,
        (__attribute__((address_space(3))) void*)(lb + j * 1024 + l * 16),
        16, 0, 0);
  }
}

__device__ __forceinline__ void mfma_hi(const char* lb, int l,
    const short8 ah0[4], const short8 al0[4],
    const short8 ah1[4], const short8 al1[4], f32x4 acc[2][8]) {
#pragma unroll
  for (int kt = 0; kt < 4; kt++) {
#pragma unroll
    for (int t = 0; t < 8; t++) {
      short8 bh = *(const short8*)(lb + (t * 4 + kt) * 1024 + l * 16);
      acc[0][t] = __builtin_amdgcn_mfma_f32_16x16x32_bf16(ah0[kt], bh, acc[0][t], 0, 0, 0);
      acc[0][t] = __builtin_amdgcn_mfma_f32_16x16x32_bf16(al0[kt], bh, acc[0][t], 0, 0, 0);
      acc[1][t] = __builtin_amdgcn_mfma_f32_16x16x32_bf16(ah1[kt], bh, acc[1][t], 0, 0, 0);
      acc[1][t] = __builtin_amdgcn_mfma_f32_16x16x32_bf16(al1[kt], bh, acc[1][t], 0, 0, 0);
    }
  }
}

__device__ __forceinline__ void mfma_lo(const char* lb, int l,
    const short8 ah0[4], const short8 ah1[4], f32x4 acc[2][8]) {
#pragma unroll
  for (int kt = 0; kt < 4; kt++) {
#pragma unroll
    for (int t = 0; t < 8; t++) {
      short8 bl = *(const short8*)(lb + (t * 4 + kt) * 1024 + l * 16);
      acc[0][t] = __builtin_amdgcn_mfma_f32_16x16x32_bf16(ah0[kt], bl, acc[0][t], 0, 0, 0);
      acc[1][t] = __builtin_amdgcn_mfma_f32_16x16x32_bf16(ah1[kt], bl, acc[1][t], 0, 0, 0);
    }
  }
}

__device__ __forceinline__ void zero_acc(f32x4 acc[2][8]) {
#pragma unroll
  for (int f = 0; f < 2; f++)
#pragma unroll
    for (int t = 0; t < 8; t++) acc[f][t] = (f32x4){0.f, 0.f, 0.f, 0.f};
}

// fragments -> per-wave LDS repack -> coalesced 8B/lane stores
__device__ __forceinline__ void epilogue(f32x4 acc[2][8],
    const float* __restrict__ bias, ushort_t* __restrict__ outp,
    int ostride, float scale, ushort_t* lo_, int m0, int n, int l) {
  const int lm = l & 15, lq = l >> 4;
#pragma unroll
  for (int t = 0; t < 8; t++) {
    const int col = t * 16 + lm;
    const float bv_ = bias[col];
#pragma unroll
    for (int f = 0; f < 2; f++) {
#pragma unroll
      for (int r = 0; r < 4; r++) {
        lo_[(f * 16 + lq * 4 + r) * OSTRIDE_LDS + col] = f2bf((acc[f][t][r] + bv_) * scale);
      }
    }
  }
  asm volatile("s_waitcnt lgkmcnt(0)" ::: "memory");   // wave-local ordering
  __builtin_amdgcn_wave_barrier();

  const int rr = l >> 5;
  const int ch = l & 31;
#pragma unroll
  for (int it = 0; it < 16; it++) {
    const int rw = it * 2 + rr;                // row within wave, 0..31
    const int grow = m0 + rw;
    short4v val = *(short4v*)(lo_ + rw * OSTRIDE_LDS + ch * 4);
    if (grow < n) *(short4v*)(outp + (size_t)grow * ostride + ch * 4) = val;
  }
  MEMPIN();                                    // pin stores before next barrier
}

// One block = 128 rows (4 waves x 32 rows, 2 A-fragments each). 6 W-phases
// (q.hi, q.lo, k.hi, k.lo, v.hi, v.lo) round-robin two 32KB LDS buffers;
// phase p+1's global_load_lds fly under phase p's MFMAs; counted vmcnt(8)
// (never 0 mid-loop) + raw s_barrier instead of __syncthreads drains.
__global__ __launch_bounds__(256) void qkv_fused_kernel(
    const float* __restrict__ h,
    const float* __restrict__ bq, const float* __restrict__ bk,
    const float* __restrict__ bv,
    const ushort_t* __restrict__ whi, const ushort_t* __restrict__ wlo,
    ushort_t* __restrict__ qs, ushort_t* __restrict__ ks, ushort_t* __restrict__ vs,
    int n) {
  __shared__ __align__(16) char lds_b[2][32 * 1024];         // B double-buffer
  __shared__ ushort_t lds_r[4][32 * OSTRIDE_LDS];            // repack, 33 KB

  const int wave = threadIdx.x >> 6;
  const int l = threadIdx.x & 63;
  const int lm = l & 15;
  const int lq = l >> 4;
  const int m0 = blockIdx.x * 128 + wave * 32;

  stage_w(whi, lds_b[0], wave, l);             // phase 0 (q.hi) in flight early

  // --- A: load h rows and split to bf16 hi/lo ONCE; reused by all 3 projections.
  int ar0 = m0 + lm;        if (ar0 >= n) ar0 = n - 1;
  int ar1 = m0 + 16 + lm;   if (ar1 >= n) ar1 = n - 1;
  const float* ap0 = h + (size_t)ar0 * HID + lq * 8;
  const float* ap1 = h + (size_t)ar1 * HID + lq * 8;
  short8 ah0[4], al0[4], ah1[4], al1[4];
#pragma unroll
  for (int kt = 0; kt < 4; kt++) {
    split8p(ap0 + kt * 32, ah0[kt], al0[kt]);
    split8p(ap1 + kt * 32, ah1[kt], al1[kt]);
  }

  f32x4 acc[2][8];
  ushort_t* lo_ = lds_r[wave];

  // ---- p=0: compute q.hi (buf0), prefetch q.lo (buf1) ----
  stage_w(wlo, lds_b[1], wave, l);
  WAITV(8); BARRIER();
  zero_acc(acc);
  mfma_hi(lds_b[0], l, ah0, al0, ah1, al1, acc);
  BARRIER();
  // ---- p=1: compute q.lo (buf1), prefetch k.hi (buf0), epilogue q ----
  stage_w(whi + 16384, lds_b[0], wave, l);
  WAITV(8); BARRIER();
  mfma_lo(lds_b[1], l, ah0, ah1, acc);
  epilogue(acc, bq, qs, 256, 0.25f, lo_, m0, n, l);
  BARRIER();
  // ---- p=2: compute k.hi (buf0), prefetch k.lo (buf1) ----
  stage_w(wlo + 16384, lds_b[1], wave, l);
  WAITV(8); BARRIER();
  zero_acc(acc);
  mfma_hi(lds_b[0], l, ah0, al0, ah1, al1, acc);
  BARRIER();
  // ---- p=3: compute k.lo (buf1), prefetch v.hi (buf0), epilogue k ----
  stage_w(whi + 32768, lds_b[0], wave, l);
  WAITV(8); BARRIER();
  mfma_lo(lds_b[1], l, ah0, ah1, acc);
  epilogue(acc, bk, ks, 128, 1.0f, lo_, m0, n, l);
  BARRIER();
  // ---- p=4: compute v.hi (buf0), prefetch v.lo (buf1) ----
  stage_w(wlo + 32768, lds_b[1], wave, l);
  WAITV(8); BARRIER();
  zero_acc(acc);
  mfma_hi(lds_b[0], l, ah0, al0, ah1, al1, acc);
  BARRIER();
  // ---- p=5: compute v.lo (buf1), epilogue v ----
  WAITV(0); BARRIER();
  mfma_lo(lds_b[1], l, ah0, ah1, acc);
  epilogue(acc, bv, vs, 128, 1.0f, lo_, m0, n, l);
}

// ---------------- Phase 2: fused scores + softmax + aggregate ----------------
// TWO rows per wave (was one): ~42 loads in flight per wave instead of ~21;
// per-row fixed cost (shuffles, barriers) amortized 2x.
__global__ __launch_bounds__(256) void attn_kernel(
    const int* __restrict__ col_ind,
    const ushort_t* __restrict__ qs, const ushort_t* __restrict__ ks,
    const ushort_t* __restrict__ vs, float* __restrict__ out, int n) {
  __shared__ __align__(16) float lds_attn[4][2][DEG * 8];  // [wave][row][edge*head]

  const int wv = threadIdx.x >> 6;
  const int l = threadIdx.x & 63;
  const int lm = l & 15;
  const int lq = l >> 4;

  int row0 = (blockIdx.x * 4 + wv) * 2;
  if (row0 >= n) row0 = n - 1;
  int row1 = row0 + 1;
  if (row1 >= n) row1 = n - 1;
  const int eb0 = row0 * DEG, eb1 = row1 * DEG;

  const int cm0 = col_ind[eb0 + lm];               // this lane's A-operand edges
  const int cm1 = col_ind[eb1 + lm];
  const ushort_t* kp0 = ks + (size_t)cm0 * HID + lq * 8;
  const ushort_t* kp1 = ks + (size_t)cm1 * HID + lq * 8;
  const ushort_t* qp0 = qs + (size_t)row0 * 256;   // q embedded in out row
  const ushort_t* qp1 = qs + (size_t)row1 * 256;

  short8 af0[4], af1[4];
  ushort_t qv0[4], qv1[4];
#pragma unroll
  for (int kt = 0; kt < 4; kt++) {
    af0[kt] = *(const short8*)(kp0 + kt * 32);
    af1[kt] = *(const short8*)(kp1 + kt * 32);
    qv0[kt] = (lm < 8) ? qp0[kt * 32 + lq * 8 + lm] : (ushort_t)0;
    qv1[kt] = (lm < 8) ? qp1[kt * 32 + lq * 8 + lm] : (ushort_t)0;
  }

  uint32 vreg0[DEG], vreg1[DEG];
#pragma unroll
  for (int e = 0; e < DEG; e++) {
    const int c0 = col_ind[eb0 + e];               // wave-uniform -> s_load
    const int c1 = col_ind[eb1 + e];
    vreg0[e] = *(const uint32*)(vs + (size_t)c0 * HID + 2 * l);
    vreg1[e] = *(const uint32*)(vs + (size_t)c1 * HID + 2 * l);
  }

  f32x4 acc0 = (f32x4){0.f, 0.f, 0.f, 0.f};
  f32x4 acc1 = (f32x4){0.f, 0.f, 0.f, 0.f};
#pragma unroll
  for (int kt = 0; kt < 4; kt++) {
    short8 bf0, bf1;
#pragma unroll
    for (int j = 0; j < 8; j++) {
      bf0[j] = (lm == j) ? (short)qv0[kt] : (short)0;
      bf1[j] = (lm == j) ? (short)qv1[kt] : (short)0;
    }
    acc0 = __builtin_amdgcn_mfma_f32_16x16x32_bf16(af0[kt], bf0, acc0, 0, 0, 0);
    acc1 = __builtin_amdgcn_mfma_f32_16x16x32_bf16(af1[kt], bf1, acc1, 0, 0, 0);
  }

  // row0 softmax
  float m0 = fmaxf(fmaxf(acc0[0], acc0[1]), fmaxf(acc0[2], acc0[3]));
  m0 = fmaxf(m0, __shfl_xor(m0, 16, 64));
  m0 = fmaxf(m0, __shfl_xor(m0, 32, 64));
  float e00 = __expf(acc0[0] - m0), e01 = __expf(acc0[1] - m0);
  float e02 = __expf(acc0[2] - m0), e03 = __expf(acc0[3] - m0);
  float s0 = e00 + e01 + e02 + e03;
  s0 += __shfl_xor(s0, 16, 64);
  s0 += __shfl_xor(s0, 32, 64);
  const float inv0 = 1.0f / s0;
  // row1 softmax
  float m1 = fmaxf(fmaxf(acc1[0], acc1[1]), fmaxf(acc1[2], acc1[3]));
  m1 = fmaxf(m1, __shfl_xor(m1, 16, 64));
  m1 = fmaxf(m1, __shfl_xor(m1, 32, 64));
  float e10 = __expf(acc1[0] - m1), e11 = __expf(acc1[1] - m1);
  float e12 = __expf(acc1[2] - m1), e13 = __expf(acc1[3] - m1);
  float s1 = e10 + e11 + e12 + e13;
  s1 += __shfl_xor(s1, 16, 64);
  s1 += __shfl_xor(s1, 32, 64);
  const float inv1 = 1.0f / s1;

  float* ap0 = lds_attn[wv][0];
  float* ap1 = lds_attn[wv][1];
  if (lm < 8) {
    ap0[(lq * 4 + 0) * 8 + lm] = e00 * inv0;
    ap0[(lq * 4 + 1) * 8 + lm] = e01 * inv0;
    ap0[(lq * 4 + 2) * 8 + lm] = e02 * inv0;
    ap0[(lq * 4 + 3) * 8 + lm] = e03 * inv0;
    ap1[(lq * 4 + 0) * 8 + lm] = e10 * inv1;
    ap1[(lq * 4 + 1) * 8 + lm] = e11 * inv1;
    ap1[(lq * 4 + 2) * 8 + lm] = e12 * inv1;
    ap1[(lq * 4 + 3) * 8 + lm] = e13 * inv1;
  }
  asm volatile("s_waitcnt lgkmcnt(0)" ::: "memory");
  __builtin_amdgcn_wave_barrier();

  const int h0 = 2 * (l & 3);
  float o00 = 0.f, o01 = 0.f, o10 = 0.f, o11 = 0.f;
#pragma unroll
  for (int e = 0; e < DEG; e++) {
    const float2 a0 = *(const float2*)(ap0 + e * 8 + h0);
    const float2 a1 = *(const float2*)(ap1 + e * 8 + h0);
    o00 += a0.x * bf2f((ushort_t)(vreg0[e] & 0xffffu));
    o01 += a0.y * bf2f((ushort_t)(vreg0[e] >> 16));
    o10 += a1.x * bf2f((ushort_t)(vreg1[e] & 0xffffu));
    o11 += a1.y * bf2f((ushort_t)(vreg1[e] >> 16));
  }

  float2 oa = {o00, o01};
  float2 ob = {o10, o11};
  *(float2*)(out + (size_t)row0 * HID + 2 * l) = oa;  // overwrites consumed q
  *(float2*)(out + (size_t)row1 * HID + 2 * l) = ob;
}

extern "C" void kernel_launch(void* const* d_in, const int* in_sizes, int n_in,
                              void* d_out, int out_size, void* d_ws, size_t ws_size,
                              hipStream_t stream) {
  const float* h  = (const float*)d_in[0];
  const float* Wq = (const float*)d_in[1];
  const float* bq = (const float*)d_in[2];
  const float* Wk = (const float*)d_in[3];
  const float* bk = (const float*)d_in[4];
  const float* Wv = (const float*)d_in[5];
  const float* bv = (const float*)d_in[6];
  // d_in[7] = row_ptr (fixed degree 16) — unused
  const int* col_ind = (const int*)d_in[8];
  // d_in[9] = num_heads (= 8) — hardcoded in layout math

  const int n = in_sizes[0] / HID;  // 50000

  // ws layout (~25.8 MB): k, v bf16 tables + W hi/lo splits. q (bf16) lives in
  // the first 256 B of each row's 512 B fp32 out slot.
  ushort_t* ks  = (ushort_t*)d_ws;
  ushort_t* vs  = ks + (size_t)n * HID;
  ushort_t* whi = vs + (size_t)n * HID;
  ushort_t* wlo = whi + 3 * 16384;
  ushort_t* qs  = (ushort_t*)d_out;
  float* outf   = (float*)d_out;

  const int npairs = (n + 1) / 2;
  prep_kernel<<<24, 256, 0, stream>>>(Wq, Wk, Wv, whi, wlo);
  qkv_fused_kernel<<<(n + 127) / 128, 256, 0, stream>>>(h, bq, bk, bv, whi, wlo, qs, ks, vs, n);
  attn_kernel<<<(npairs + 3) / 4, 256, 0, stream>>>(col_ind, qs, ks, vs, outf, n);
}

// Round 2
// 185.175 us; speedup vs baseline: 1.0369x; 1.0369x over previous
//
#include <hip/hip_runtime.h>
#include <hip/hip_bf16.h>

// SparseMHA, fixed out-degree CSR graph attention. fp32 in/out.
// r10 -> r11:
//  * attn: reverted to r9 exactly (2-rows/wave pushed VGPR 44->64 = m69
//    occupancy cliff, occ 45->36%, +4us). Parallelism is wave-count-bound.
//  * qkv: r10's 2x32KB double-buffer cost a block/CU (97KB LDS -> 1 block/CU,
//    two dispatch rounds, lost inter-block overlap, ~+15us). Keep the counted
//    vmcnt pipeline but stage W in 16KB HALVES: 2x16KB buffers = same 65KB
//    footprint as r9 (2 blocks/CU preserved) while stage s+1's DMA flies
//    under stage s's MFMAs. 12 stages, WAITV(4) per phase (0 only at tail).

typedef unsigned short ushort_t;
typedef unsigned int uint32;
typedef short short8 __attribute__((ext_vector_type(8)));
typedef short short4v __attribute__((ext_vector_type(4)));
typedef float f32x4 __attribute__((ext_vector_type(4)));

#define HID 128
#define DEG 16
#define OSTRIDE_LDS 132   // ushort row stride in LDS repack (bank-conflict-free)

__device__ __forceinline__ float bf2f(ushort_t u) {
  uint32 x = ((uint32)u) << 16;
  return __builtin_bit_cast(float, x);
}
__device__ __forceinline__ ushort_t f2bf(float f) {
  uint32 u = __builtin_bit_cast(uint32, f);
  u += 0x7fffu + ((u >> 16) & 1u);   // RNE
  return (ushort_t)(u >> 16);
}

// Packed split of 2 fp32 -> packed bf16 hi pair + lo pair (RNE, v_cvt_pk path).
__device__ __forceinline__ void split2(float x, float y, uint32& hi, uint32& lo) {
  __hip_bfloat162 h2 = __float22bfloat162_rn(float2{x, y});
  __builtin_memcpy(&hi, &h2, 4);
  float hx = __builtin_bit_cast(float, hi << 16);
  float hy = __builtin_bit_cast(float, hi & 0xffff0000u);
  __hip_bfloat162 l2 = __float22bfloat162_rn(float2{x - hx, y - hy});
  __builtin_memcpy(&lo, &l2, 4);
}

__device__ __forceinline__ void split8v(float4 a, float4 b, short8& hi, short8& lo) {
  uint32* hu = (uint32*)&hi;
  uint32* lu = (uint32*)&lo;
  split2(a.x, a.y, hu[0], lu[0]);
  split2(a.z, a.w, hu[1], lu[1]);
  split2(b.x, b.y, hu[2], lu[2]);
  split2(b.z, b.w, hu[3], lu[3]);
}

__device__ __forceinline__ void split8p(const float* __restrict__ p, short8& hi, short8& lo) {
  float4 a = *(const float4*)p;
  float4 b = *(const float4*)(p + 4);
  split8v(a, b, hi, lo);
}

// ---------------- Phase 0: pre-split Wq|Wk|Wv into bf16 hi/lo ----------------
__global__ __launch_bounds__(256) void prep_kernel(
    const float* __restrict__ Wq, const float* __restrict__ Wk,
    const float* __restrict__ Wv,
    ushort_t* __restrict__ whi, ushort_t* __restrict__ wlo) {
  const int idx8 = (blockIdx.x * 256 + threadIdx.x) * 8;   // [0, 49152)
  const float* W = (idx8 < 16384) ? Wq : (idx8 < 32768) ? Wk : Wv;
  const int off = idx8 & 16383;
  short8 hi, lo;
  split8p(W + off, hi, lo);
  *(short8*)(whi + idx8) = hi;
  *(short8*)(wlo + idx8) = lo;
}

// ---------------- Phase 1: fused Q+K+V projection, half-pipelined ----------------
#define WAITV(n) asm volatile("s_waitcnt vmcnt(" #n ")" ::: "memory")
#define BARRIER() __builtin_amdgcn_s_barrier()
#define MEMPIN() asm volatile("" ::: "memory")

// Fragment j = t*4+kt (1KB each): lane l holds bytes slot*1024 + l*16,
// slot = j & 15 within a 16KB half-buffer. Half h covers t in [4h, 4h+4).
// Each wave stages 4 fragments (4 loads) per half.
__device__ __forceinline__ void stage_half(const ushort_t* __restrict__ W,
                                           char* lb, int half, int wave, int l) {
  const int lm = l & 15, lq = l >> 4;
#pragma unroll
  for (int jj = 0; jj < 4; jj++) {
    const int j = half * 16 + wave * 4 + jj;   // global fragment id
    const int t = j >> 2, kt = j & 3;
    const ushort_t* gp = W + (t * 16 + lm) * HID + kt * 32 + lq * 8;
    __builtin_amdgcn_global_load_lds(
        (const __attribute__((address_space(1))) void*)gp,
        (__attribute__((address_space(3))) void*)(lb + (j & 15) * 1024 + l * 16),
        16, 0, 0);
  }
}

__device__ __forceinline__ void mfma_half_hi(const char* lb, int tbase, int l,
    const short8 ah0[4], const short8 al0[4],
    const short8 ah1[4], const short8 al1[4], f32x4 acc[2][8]) {
#pragma unroll
  for (int kt = 0; kt < 4; kt++) {
#pragma unroll
    for (int tt = 0; tt < 4; tt++) {
      const int t = tbase + tt;
      short8 bh = *(const short8*)(lb + (tt * 4 + kt) * 1024 + l * 16);
      acc[0][t] = __builtin_amdgcn_mfma_f32_16x16x32_bf16(ah0[kt], bh, acc[0][t], 0, 0, 0);
      acc[0][t] = __builtin_amdgcn_mfma_f32_16x16x32_bf16(al0[kt], bh, acc[0][t], 0, 0, 0);
      acc[1][t] = __builtin_amdgcn_mfma_f32_16x16x32_bf16(ah1[kt], bh, acc[1][t], 0, 0, 0);
      acc[1][t] = __builtin_amdgcn_mfma_f32_16x16x32_bf16(al1[kt], bh, acc[1][t], 0, 0, 0);
    }
  }
}

__device__ __forceinline__ void mfma_half_lo(const char* lb, int tbase, int l,
    const short8 ah0[4], const short8 ah1[4], f32x4 acc[2][8]) {
#pragma unroll
  for (int kt = 0; kt < 4; kt++) {
#pragma unroll
    for (int tt = 0; tt < 4; tt++) {
      const int t = tbase + tt;
      short8 bl = *(const short8*)(lb + (tt * 4 + kt) * 1024 + l * 16);
      acc[0][t] = __builtin_amdgcn_mfma_f32_16x16x32_bf16(ah0[kt], bl, acc[0][t], 0, 0, 0);
      acc[1][t] = __builtin_amdgcn_mfma_f32_16x16x32_bf16(ah1[kt], bl, acc[1][t], 0, 0, 0);
    }
  }
}

__device__ __forceinline__ void zero_acc(f32x4 acc[2][8]) {
#pragma unroll
  for (int f = 0; f < 2; f++)
#pragma unroll
    for (int t = 0; t < 8; t++) acc[f][t] = (f32x4){0.f, 0.f, 0.f, 0.f};
}

// fragments -> per-wave LDS repack -> coalesced 8B/lane stores
__device__ __forceinline__ void epilogue(f32x4 acc[2][8],
    const float* __restrict__ bias, ushort_t* __restrict__ outp,
    int ostride, float scale, ushort_t* lo_, int m0, int n, int l) {
  const int lm = l & 15, lq = l >> 4;
#pragma unroll
  for (int t = 0; t < 8; t++) {
    const int col = t * 16 + lm;
    const float bv_ = bias[col];
#pragma unroll
    for (int f = 0; f < 2; f++) {
#pragma unroll
      for (int r = 0; r < 4; r++) {
        lo_[(f * 16 + lq * 4 + r) * OSTRIDE_LDS + col] = f2bf((acc[f][t][r] + bv_) * scale);
      }
    }
  }
  asm volatile("s_waitcnt lgkmcnt(0)" ::: "memory");   // wave-local ordering
  __builtin_amdgcn_wave_barrier();

  const int rr = l >> 5;
  const int ch = l & 31;
#pragma unroll
  for (int it = 0; it < 16; it++) {
    const int rw = it * 2 + rr;                // row within wave, 0..31
    const int grow = m0 + rw;
    short4v val = *(short4v*)(lo_ + rw * OSTRIDE_LDS + ch * 4);
    if (grow < n) *(short4v*)(outp + (size_t)grow * ostride + ch * 4) = val;
  }
  MEMPIN();                                    // pin stores before next barrier
}

// One block = 128 rows (4 waves x 32 rows, 2 A-fragments each). 12 stages of
// 16KB (q.hi.0, q.hi.1, q.lo.0, q.lo.1, k.hi.0, ...) round-robin two 16KB
// buffers (total LDS 65KB, same as r9 -> 2 blocks/CU). Stage s+1's
// global_load_lds fly under stage s's MFMAs; per-phase WAITV(4) drains only
// the stage about to be read (plus any epilogue stores), never the prefetch.
__global__ __launch_bounds__(256) void qkv_fused_kernel(
    const float* __restrict__ h,
    const float* __restrict__ bq, const float* __restrict__ bk,
    const float* __restrict__ bv,
    const ushort_t* __restrict__ whi, const ushort_t* __restrict__ wlo,
    ushort_t* __restrict__ qs, ushort_t* __restrict__ ks, ushort_t* __restrict__ vs,
    int n) {
  __shared__ __align__(16) char lds_b[2][16 * 1024];         // half double-buffer
  __shared__ ushort_t lds_r[4][32 * OSTRIDE_LDS];            // repack, 33 KB

  const int wave = threadIdx.x >> 6;
  const int l = threadIdx.x & 63;
  const int lm = l & 15;
  const int lq = l >> 4;
  const int m0 = blockIdx.x * 128 + wave * 32;

  // --- A: load h rows FIRST (oldest in vmcnt queue), split to bf16 hi/lo
  // ONCE; reused by all 3 projections. Staging loads issued after so the
  // split's compiler-inserted waits leave the stage DMA in flight.
  int ar0 = m0 + lm;        if (ar0 >= n) ar0 = n - 1;
  int ar1 = m0 + 16 + lm;   if (ar1 >= n) ar1 = n - 1;
  const float* ap0 = h + (size_t)ar0 * HID + lq * 8;
  const float* ap1 = h + (size_t)ar1 * HID + lq * 8;
  float4 a0[4][2], a1[4][2];
#pragma unroll
  for (int kt = 0; kt < 4; kt++) {
    a0[kt][0] = *(const float4*)(ap0 + kt * 32);
    a0[kt][1] = *(const float4*)(ap0 + kt * 32 + 4);
    a1[kt][0] = *(const float4*)(ap1 + kt * 32);
    a1[kt][1] = *(const float4*)(ap1 + kt * 32 + 4);
  }

  stage_half(whi, lds_b[0], 0, wave, l);       // s0: q.hi half0
  stage_half(whi, lds_b[1], 1, wave, l);       // s1: q.hi half1

  short8 ah0[4], al0[4], ah1[4], al1[4];
#pragma unroll
  for (int kt = 0; kt < 4; kt++) {
    split8v(a0[kt][0], a0[kt][1], ah0[kt], al0[kt]);
    split8v(a1[kt][0], a1[kt][1], ah1[kt], al1[kt]);
  }

  f32x4 acc[2][8];
  ushort_t* lo_ = lds_r[wave];

  // ---- phase 0: compute s0 (buf0: q.hi t0..3) ----
  WAITV(4); BARRIER();
  zero_acc(acc);
  mfma_half_hi(lds_b[0], 0, l, ah0, al0, ah1, al1, acc);
  BARRIER();
  stage_half(wlo, lds_b[0], 0, wave, l);       // s2: q.lo half0
  // ---- phase 1: compute s1 (buf1: q.hi t4..7) ----
  WAITV(4); BARRIER();
  mfma_half_hi(lds_b[1], 4, l, ah0, al0, ah1, al1, acc);
  BARRIER();
  stage_half(wlo, lds_b[1], 1, wave, l);       // s3: q.lo half1
  // ---- phase 2: compute s2 (buf0: q.lo t0..3) ----
  WAITV(4); BARRIER();
  mfma_half_lo(lds_b[0], 0, l, ah0, ah1, acc);
  BARRIER();
  stage_half(whi + 16384, lds_b[0], 0, wave, l); // s4: k.hi half0
  // ---- phase 3: compute s3 (buf1: q.lo t4..7) + epilogue q ----
  WAITV(4); BARRIER();
  mfma_half_lo(lds_b[1], 4, l, ah0, ah1, acc);
  epilogue(acc, bq, qs, 256, 0.25f, lo_, m0, n, l);
  BARRIER();
  stage_half(whi + 16384, lds_b[1], 1, wave, l); // s5: k.hi half1
  // ---- phase 4: compute s4 (buf0: k.hi t0..3) ----
  WAITV(4); BARRIER();
  zero_acc(acc);
  mfma_half_hi(lds_b[0], 0, l, ah0, al0, ah1, al1, acc);
  BARRIER();
  stage_half(wlo + 16384, lds_b[0], 0, wave, l); // s6: k.lo half0
  // ---- phase 5: compute s5 (buf1: k.hi t4..7) ----
  WAITV(4); BARRIER();
  mfma_half_hi(lds_b[1], 4, l, ah0, al0, ah1, al1, acc);
  BARRIER();
  stage_half(wlo + 16384, lds_b[1], 1, wave, l); // s7: k.lo half1
  // ---- phase 6: compute s6 (buf0: k.lo t0..3) ----
  WAITV(4); BARRIER();
  mfma_half_lo(lds_b[0], 0, l, ah0, ah1, acc);
  BARRIER();
  stage_half(whi + 32768, lds_b[0], 0, wave, l); // s8: v.hi half0
  // ---- phase 7: compute s7 (buf1: k.lo t4..7) + epilogue k ----
  WAITV(4); BARRIER();
  mfma_half_lo(lds_b[1], 4, l, ah0, ah1, acc);
  epilogue(acc, bk, ks, 128, 1.0f, lo_, m0, n, l);
  BARRIER();
  stage_half(whi + 32768, lds_b[1], 1, wave, l); // s9: v.hi half1
  // ---- phase 8: compute s8 (buf0: v.hi t0..3) ----
  WAITV(4); BARRIER();
  zero_acc(acc);
  mfma_half_hi(lds_b[0], 0, l, ah0, al0, ah1, al1, acc);
  BARRIER();
  stage_half(wlo + 32768, lds_b[0], 0, wave, l); // s10: v.lo half0
  // ---- phase 9: compute s9 (buf1: v.hi t4..7) ----
  WAITV(4); BARRIER();
  mfma_half_hi(lds_b[1], 4, l, ah0, al0, ah1, al1, acc);
  BARRIER();
  stage_half(wlo + 32768, lds_b[1], 1, wave, l); // s11: v.lo half1
  // ---- phase 10: compute s10 (buf0: v.lo t0..3) ----
  WAITV(4); BARRIER();
  mfma_half_lo(lds_b[0], 0, l, ah0, ah1, acc);
  BARRIER();
  // ---- phase 11: compute s11 (buf1: v.lo t4..7) + epilogue v ----
  WAITV(0); BARRIER();
  mfma_half_lo(lds_b[1], 4, l, ah0, ah1, acc);
  epilogue(acc, bv, vs, 128, 1.0f, lo_, m0, n, l);
}

// ---------------- Phase 2: fused scores + softmax + aggregate ----------------
// One wave per row (r9 version: wave-count-bound, VGPR 44, occ ~45%).
__global__ __launch_bounds__(256) void attn_kernel(
    const int* __restrict__ col_ind,
    const ushort_t* __restrict__ qs, const ushort_t* __restrict__ ks,
    const ushort_t* __restrict__ vs, float* __restrict__ out, int n) {
  __shared__ __align__(16) float lds_attn[4 * DEG * 8];  // [wave][edge][head]

  const int wv = threadIdx.x >> 6;
  const int l = threadIdx.x & 63;
  const int lm = l & 15;
  const int lq = l >> 4;

  int row = blockIdx.x * 4 + wv;
  if (row >= n) row = n - 1;
  const int eb = row * DEG;

  const int cm = col_ind[eb + lm];                 // this lane's A-operand edge
  const ushort_t* kp = ks + (size_t)cm * HID + lq * 8;
  const ushort_t* qp = qs + (size_t)row * 256;     // q embedded in out row

  short8 af[4];
  ushort_t qv[4];
#pragma unroll
  for (int kt = 0; kt < 4; kt++) {
    af[kt] = *(const short8*)(kp + kt * 32);
    qv[kt] = (lm < 8) ? qp[kt * 32 + lq * 8 + lm] : (ushort_t)0;
  }

  uint32 vreg[DEG];
#pragma unroll
  for (int e = 0; e < DEG; e++) {
    const int c = col_ind[eb + e];                 // wave-uniform -> s_load
    vreg[e] = *(const uint32*)(vs + (size_t)c * HID + 2 * l);
  }

  f32x4 acc = (f32x4){0.f, 0.f, 0.f, 0.f};
#pragma unroll
  for (int kt = 0; kt < 4; kt++) {
    short8 bf;
#pragma unroll
    for (int j = 0; j < 8; j++) bf[j] = (lm == j) ? (short)qv[kt] : (short)0;
    acc = __builtin_amdgcn_mfma_f32_16x16x32_bf16(af[kt], bf, acc, 0, 0, 0);
  }

  float m = fmaxf(fmaxf(acc[0], acc[1]), fmaxf(acc[2], acc[3]));
  m = fmaxf(m, __shfl_xor(m, 16, 64));
  m = fmaxf(m, __shfl_xor(m, 32, 64));
  float e0 = __expf(acc[0] - m), e1 = __expf(acc[1] - m);
  float e2 = __expf(acc[2] - m), e3 = __expf(acc[3] - m);
  float s = e0 + e1 + e2 + e3;
  s += __shfl_xor(s, 16, 64);
  s += __shfl_xor(s, 32, 64);
  const float inv = 1.0f / s;

  float* ap = &lds_attn[wv * (DEG * 8)];
  if (lm < 8) {
    ap[(lq * 4 + 0) * 8 + lm] = e0 * inv;
    ap[(lq * 4 + 1) * 8 + lm] = e1 * inv;
    ap[(lq * 4 + 2) * 8 + lm] = e2 * inv;
    ap[(lq * 4 + 3) * 8 + lm] = e3 * inv;
  }
  asm volatile("s_waitcnt lgkmcnt(0)" ::: "memory");
  __builtin_amdgcn_wave_barrier();

  const int h0 = 2 * (l & 3);
  float o0 = 0.f, o1 = 0.f;
#pragma unroll
  for (int e = 0; e < DEG; e++) {
    const float2 at = *(const float2*)(ap + e * 8 + h0);
    o0 += at.x * bf2f((ushort_t)(vreg[e] & 0xffffu));
    o1 += at.y * bf2f((ushort_t)(vreg[e] >> 16));
  }

  float2 o = {o0, o1};
  *(float2*)(out + (size_t)row * HID + 2 * l) = o;  // overwrites consumed q
}

extern "C" void kernel_launch(void* const* d_in, const int* in_sizes, int n_in,
                              void* d_out, int out_size, void* d_ws, size_t ws_size,
                              hipStream_t stream) {
  const float* h  = (const float*)d_in[0];
  const float* Wq = (const float*)d_in[1];
  const float* bq = (const float*)d_in[2];
  const float* Wk = (const float*)d_in[3];
  const float* bk = (const float*)d_in[4];
  const float* Wv = (const float*)d_in[5];
  const float* bv = (const float*)d_in[6];
  // d_in[7] = row_ptr (fixed degree 16) — unused
  const int* col_ind = (const int*)d_in[8];
  // d_in[9] = num_heads (= 8) — hardcoded in layout math

  const int n = in_sizes[0] / HID;  // 50000

  // ws layout (~25.8 MB): k, v bf16 tables + W hi/lo splits. q (bf16) lives in
  // the first 256 B of each row's 512 B fp32 out slot.
  ushort_t* ks  = (ushort_t*)d_ws;
  ushort_t* vs  = ks + (size_t)n * HID;
  ushort_t* whi = vs + (size_t)n * HID;
  ushort_t* wlo = whi + 3 * 16384;
  ushort_t* qs  = (ushort_t*)d_out;
  float* outf   = (float*)d_out;

  prep_kernel<<<24, 256, 0, stream>>>(Wq, Wk, Wv, whi, wlo);
  qkv_fused_kernel<<<(n + 127) / 128, 256, 0, stream>>>(h, bq, bk, bv, whi, wlo, qs, ks, vs, n);
  attn_kernel<<<(n + 3) / 4, 256, 0, stream>>>(col_ind, qs, ks, vs, outf, n);
}

// Round 3
// 175.257 us; speedup vs baseline: 1.0956x; 1.0566x over previous
//
#include <hip/hip_runtime.h>
#include <hip/hip_bf16.h>

// SparseMHA, fixed out-degree CSR graph attention. fp32 in/out.
// r11 -> r12:
//  * qkv: reverted to r9-exact (6-phase __syncthreads version). Both pipelining
//    attempts (r10 2x32KB dbuf, r11 16KB halves) regressed (+14.5/+11.3us):
//    with 2 blocks/CU the inter-block overlap already hides stage DMA; extra
//    barriers only add cost. Schedule is done; do not touch.
//  * attn: evidence (r10: +60% in-flight loads -> BW DROPPED 3.87->3.6 TB/s;
//    occ 45% with zero resource caps) says the limiter is L2 REQUEST RATE,
//    not bytes or occupancy. K fragment loads touched 16 half-lines per instr
//    (kt pairs share 128B lines across instrs -> 2x requests for same lines).
//    Now: K gathered coalesced (1 instr = 4 full rows, unique lines only)
//    through a per-wave XOR-swizzled 4KB LDS tile; af fragments read from LDS
//    (2-way banks = free). q row: one 16-lane load -> LDS -> ds_read_u16.
//    Edge cols for the coalesced layout via ds_bpermute (no extra L2 traffic).
//    ~-30% L2 requests/wave. Numerics bit-identical.

typedef unsigned short ushort_t;
typedef unsigned int uint32;
typedef short short8 __attribute__((ext_vector_type(8)));
typedef short short4v __attribute__((ext_vector_type(4)));
typedef float f32x4 __attribute__((ext_vector_type(4)));

#define HID 128
#define DEG 16
#define OSTRIDE_LDS 132   // ushort row stride in LDS repack (bank-conflict-free)

__device__ __forceinline__ float bf2f(ushort_t u) {
  uint32 x = ((uint32)u) << 16;
  return __builtin_bit_cast(float, x);
}
__device__ __forceinline__ ushort_t f2bf(float f) {
  uint32 u = __builtin_bit_cast(uint32, f);
  u += 0x7fffu + ((u >> 16) & 1u);   // RNE
  return (ushort_t)(u >> 16);
}

// Packed split of 2 fp32 -> packed bf16 hi pair + lo pair (RNE, v_cvt_pk path).
__device__ __forceinline__ void split2(float x, float y, uint32& hi, uint32& lo) {
  __hip_bfloat162 h2 = __float22bfloat162_rn(float2{x, y});
  __builtin_memcpy(&hi, &h2, 4);
  float hx = __builtin_bit_cast(float, hi << 16);
  float hy = __builtin_bit_cast(float, hi & 0xffff0000u);
  __hip_bfloat162 l2 = __float22bfloat162_rn(float2{x - hx, y - hy});
  __builtin_memcpy(&lo, &l2, 4);
}

__device__ __forceinline__ void split8v(float4 a, float4 b, short8& hi, short8& lo) {
  uint32* hu = (uint32*)&hi;
  uint32* lu = (uint32*)&lo;
  split2(a.x, a.y, hu[0], lu[0]);
  split2(a.z, a.w, hu[1], lu[1]);
  split2(b.x, b.y, hu[2], lu[2]);
  split2(b.z, b.w, hu[3], lu[3]);
}

__device__ __forceinline__ void split8p(const float* __restrict__ p, short8& hi, short8& lo) {
  float4 a = *(const float4*)p;
  float4 b = *(const float4*)(p + 4);
  split8v(a, b, hi, lo);
}

// ---------------- Phase 0: pre-split Wq|Wk|Wv into bf16 hi/lo ----------------
__global__ __launch_bounds__(256) void prep_kernel(
    const float* __restrict__ Wq, const float* __restrict__ Wk,
    const float* __restrict__ Wv,
    ushort_t* __restrict__ whi, ushort_t* __restrict__ wlo) {
  const int idx8 = (blockIdx.x * 256 + threadIdx.x) * 8;   // [0, 49152)
  const float* W = (idx8 < 16384) ? Wq : (idx8 < 32768) ? Wk : Wv;
  const int off = idx8 & 16383;
  short8 hi, lo;
  split8p(W + off, hi, lo);
  *(short8*)(whi + idx8) = hi;
  *(short8*)(wlo + idx8) = lo;
}

// ---------------- Phase 1: fused Q+K+V projection (r9-exact) ----------------
// One block = 128 rows (4 waves x 32 rows, 2 A-fragments each). For each of
// the 3 projections: DMA Wh fragments -> LDS (32KB, exact lane order), sync,
// MFMA (ah*bh, al*bh), sync, DMA Wl over same buffer, sync, MFMA (ah*bl),
// sync; then per-wave LDS repack -> coalesced 8B/lane stores.
// B fragment slot j = t*4+kt (1KB each): lane l holds bytes j*1024 + l*16.
__global__ __launch_bounds__(256) void qkv_fused_kernel(
    const float* __restrict__ h,
    const float* __restrict__ bq, const float* __restrict__ bk,
    const float* __restrict__ bv,
    const ushort_t* __restrict__ whi, const ushort_t* __restrict__ wlo,
    ushort_t* __restrict__ qs, ushort_t* __restrict__ ks, ushort_t* __restrict__ vs,
    int n) {
  __shared__ __align__(16) char lds_b[32 * 1024];            // B fragments (reused 6x)
  __shared__ ushort_t lds_r[4][32 * OSTRIDE_LDS];            // repack, 33 KB

  const int wave = threadIdx.x >> 6;
  const int l = threadIdx.x & 63;
  const int lm = l & 15;
  const int lq = l >> 4;
  const int m0 = blockIdx.x * 128 + wave * 32;

  // --- A: load h rows and split to bf16 hi/lo ONCE; reused by all 3 projections.
  int ar0 = m0 + lm;        if (ar0 >= n) ar0 = n - 1;
  int ar1 = m0 + 16 + lm;   if (ar1 >= n) ar1 = n - 1;
  const float* ap0 = h + (size_t)ar0 * HID + lq * 8;
  const float* ap1 = h + (size_t)ar1 * HID + lq * 8;
  short8 ah0[4], al0[4], ah1[4], al1[4];
#pragma unroll
  for (int kt = 0; kt < 4; kt++) {
    split8p(ap0 + kt * 32, ah0[kt], al0[kt]);
    split8p(ap1 + kt * 32, ah1[kt], al1[kt]);
  }

#pragma unroll 1
  for (int p = 0; p < 3; p++) {
    const ushort_t* __restrict__ Wh = whi + p * 16384;
    const ushort_t* __restrict__ Wl = wlo + p * 16384;
    const float* __restrict__ bias = (p == 0) ? bq : (p == 1) ? bk : bv;
    ushort_t* __restrict__ outp = (p == 0) ? qs : (p == 1) ? ks : vs;
    const int ostride = (p == 0) ? 256 : 128;   // q lives inside 512B fp32 out rows
    const float scale = (p == 0) ? 0.25f : 1.0f;

    f32x4 acc[2][8];
#pragma unroll
    for (int f = 0; f < 2; f++)
#pragma unroll
      for (int t = 0; t < 8; t++) acc[f][t] = (f32x4){0.f, 0.f, 0.f, 0.f};

    // ---- hi phase ----
#pragma unroll
    for (int jj = 0; jj < 8; jj++) {            // wave covers j = wave*8 + jj
      const int j = wave * 8 + jj, t = j >> 2, kt = j & 3;
      const ushort_t* gp = Wh + (t * 16 + lm) * HID + kt * 32 + lq * 8;
      __builtin_amdgcn_global_load_lds(
          (const __attribute__((address_space(1))) void*)gp,
          (__attribute__((address_space(3))) void*)(lds_b + j * 1024 + l * 16),
          16, 0, 0);
    }
    __syncthreads();                             // DMA drained for all waves
#pragma unroll
    for (int kt = 0; kt < 4; kt++) {
#pragma unroll
      for (int t = 0; t < 8; t++) {
        short8 bh = *(const short8*)(lds_b + (t * 4 + kt) * 1024 + l * 16);
        acc[0][t] = __builtin_amdgcn_mfma_f32_16x16x32_bf16(ah0[kt], bh, acc[0][t], 0, 0, 0);
        acc[0][t] = __builtin_amdgcn_mfma_f32_16x16x32_bf16(al0[kt], bh, acc[0][t], 0, 0, 0);
        acc[1][t] = __builtin_amdgcn_mfma_f32_16x16x32_bf16(ah1[kt], bh, acc[1][t], 0, 0, 0);
        acc[1][t] = __builtin_amdgcn_mfma_f32_16x16x32_bf16(al1[kt], bh, acc[1][t], 0, 0, 0);
      }
    }
    __syncthreads();                             // all waves done reading hi

    // ---- lo phase (overwrites lds_b) ----
#pragma unroll
    for (int jj = 0; jj < 8; jj++) {
      const int j = wave * 8 + jj, t = j >> 2, kt = j & 3;
      const ushort_t* gp = Wl + (t * 16 + lm) * HID + kt * 32 + lq * 8;
      __builtin_amdgcn_global_load_lds(
          (const __attribute__((address_space(1))) void*)gp,
          (__attribute__((address_space(3))) void*)(lds_b + j * 1024 + l * 16),
          16, 0, 0);
    }
    __syncthreads();
#pragma unroll
    for (int kt = 0; kt < 4; kt++) {
#pragma unroll
      for (int t = 0; t < 8; t++) {
        short8 bl = *(const short8*)(lds_b + (t * 4 + kt) * 1024 + l * 16);
        acc[0][t] = __builtin_amdgcn_mfma_f32_16x16x32_bf16(ah0[kt], bl, acc[0][t], 0, 0, 0);
        acc[1][t] = __builtin_amdgcn_mfma_f32_16x16x32_bf16(ah1[kt], bl, acc[1][t], 0, 0, 0);
      }
    }
    __syncthreads();                             // protect lds_b for next projection

    // ---- epilogue: fragments -> per-wave LDS repack -> coalesced stores ----
    ushort_t* lo_ = lds_r[wave];
#pragma unroll
    for (int t = 0; t < 8; t++) {
      const int col = t * 16 + lm;
      const float bv_ = bias[col];
#pragma unroll
      for (int f = 0; f < 2; f++) {
#pragma unroll
        for (int r = 0; r < 4; r++) {
          lo_[(f * 16 + lq * 4 + r) * OSTRIDE_LDS + col] = f2bf((acc[f][t][r] + bv_) * scale);
        }
      }
    }
    asm volatile("s_waitcnt lgkmcnt(0)" ::: "memory");   // wave-local ordering
    __builtin_amdgcn_wave_barrier();

    const int rr = l >> 5;
    const int ch = l & 31;
#pragma unroll
    for (int it = 0; it < 16; it++) {
      const int rw = it * 2 + rr;                // row within wave, 0..31
      const int grow = m0 + rw;
      short4v val = *(short4v*)(lo_ + rw * OSTRIDE_LDS + ch * 4);
      if (grow < n) *(short4v*)(outp + (size_t)grow * ostride + ch * 4) = val;
    }
  }
}

// ---------------- Phase 2: fused scores + softmax + aggregate ----------------
// One wave per row. K gathered COALESCED (4 full rows per dwordx4 instr ->
// unique L2 lines only) into a per-wave XOR-swizzled LDS tile; af fragments
// read from LDS. q row: one 16-lane load -> LDS -> 4x ds_read_u16.
__global__ __launch_bounds__(256) void attn_kernel(
    const int* __restrict__ col_ind,
    const ushort_t* __restrict__ qs, const ushort_t* __restrict__ ks,
    const ushort_t* __restrict__ vs, float* __restrict__ out, int n) {
  __shared__ __align__(16) char lds_k[4][DEG * 256];     // [wave][edge][256B] swizzled
  __shared__ __align__(16) char lds_q[4][256];           // [wave] q row
  __shared__ __align__(16) float lds_attn[4][DEG * 8];   // [wave][edge][head]

  const int wv = threadIdx.x >> 6;
  const int l = threadIdx.x & 63;
  const int lm = l & 15;
  const int lq = l >> 4;

  int row = blockIdx.x * 4 + wv;
  if (row >= n) row = n - 1;
  const int eb = row * DEG;

  // all 16 edge cols in one 64B line; every lane holds col of edge lm
  const int col16 = col_ind[eb + lm];

  // --- K gather, coalesced: instr g reads rows {g*4..g*4+3} fully
  // (lane l covers row g*4+lq, bytes lm*16..+16). Cols via bpermute (no L2).
  int4 kvec[4];
#pragma unroll
  for (int g = 0; g < 4; g++) {
    const int c = __builtin_amdgcn_ds_bpermute((g * 4 + lq) << 2, col16);
    kvec[g] = *(const int4*)(ks + (size_t)c * HID + lm * 8);
  }

  // --- q row: one 16-lane 16B load (256B total)
  int4 qrow;
  if (l < 16) qrow = *(const int4*)(qs + (size_t)row * 256 + l * 8);

  // --- V gather (already line-minimal: 256B contiguous per edge row)
  uint32 vreg[DEG];
#pragma unroll
  for (int e = 0; e < DEG; e++) {
    const int c = col_ind[eb + e];                 // wave-uniform -> s_load
    vreg[e] = *(const uint32*)(vs + (size_t)c * HID + 2 * l);
  }

  // --- spill K/q to per-wave LDS (XOR-swizzled segments: 2-way banks = free)
  char* kb = lds_k[wv];
#pragma unroll
  for (int g = 0; g < 4; g++) {
    const int e = g * 4 + lq;
    *(int4*)(kb + e * 256 + ((lm ^ (e & 7)) * 16)) = kvec[g];
  }
  if (l < 16) *(int4*)(lds_q[wv] + l * 16) = qrow;
  asm volatile("s_waitcnt lgkmcnt(0)" ::: "memory");   // wave-local ordering
  __builtin_amdgcn_wave_barrier();

  // --- read MFMA fragments back (af: lane lm = edge row, lq*16B chunk)
  short8 af[4];
  ushort_t qv[4];
#pragma unroll
  for (int kt = 0; kt < 4; kt++) {
    const int s = kt * 4 + lq;
    af[kt] = *(const short8*)(kb + lm * 256 + ((s ^ (lm & 7)) * 16));
    qv[kt] = (lm < 8) ? *(const ushort_t*)(lds_q[wv] + kt * 64 + lq * 16 + lm * 2)
                      : (ushort_t)0;
  }

  f32x4 acc = (f32x4){0.f, 0.f, 0.f, 0.f};
#pragma unroll
  for (int kt = 0; kt < 4; kt++) {
    short8 bf;
#pragma unroll
    for (int j = 0; j < 8; j++) bf[j] = (lm == j) ? (short)qv[kt] : (short)0;
    acc = __builtin_amdgcn_mfma_f32_16x16x32_bf16(af[kt], bf, acc, 0, 0, 0);
  }

  float m = fmaxf(fmaxf(acc[0], acc[1]), fmaxf(acc[2], acc[3]));
  m = fmaxf(m, __shfl_xor(m, 16, 64));
  m = fmaxf(m, __shfl_xor(m, 32, 64));
  float e0 = __expf(acc[0] - m), e1 = __expf(acc[1] - m);
  float e2 = __expf(acc[2] - m), e3 = __expf(acc[3] - m);
  float s = e0 + e1 + e2 + e3;
  s += __shfl_xor(s, 16, 64);
  s += __shfl_xor(s, 32, 64);
  const float inv = 1.0f / s;

  float* ap = lds_attn[wv];
  if (lm < 8) {
    ap[(lq * 4 + 0) * 8 + lm] = e0 * inv;
    ap[(lq * 4 + 1) * 8 + lm] = e1 * inv;
    ap[(lq * 4 + 2) * 8 + lm] = e2 * inv;
    ap[(lq * 4 + 3) * 8 + lm] = e3 * inv;
  }
  asm volatile("s_waitcnt lgkmcnt(0)" ::: "memory");
  __builtin_amdgcn_wave_barrier();

  const int h0 = 2 * (l & 3);
  float o0 = 0.f, o1 = 0.f;
#pragma unroll
  for (int e = 0; e < DEG; e++) {
    const float2 at = *(const float2*)(ap + e * 8 + h0);
    o0 += at.x * bf2f((ushort_t)(vreg[e] & 0xffffu));
    o1 += at.y * bf2f((ushort_t)(vreg[e] >> 16));
  }

  float2 o = {o0, o1};
  *(float2*)(out + (size_t)row * HID + 2 * l) = o;  // overwrites consumed q
}

extern "C" void kernel_launch(void* const* d_in, const int* in_sizes, int n_in,
                              void* d_out, int out_size, void* d_ws, size_t ws_size,
                              hipStream_t stream) {
  const float* h  = (const float*)d_in[0];
  const float* Wq = (const float*)d_in[1];
  const float* bq = (const float*)d_in[2];
  const float* Wk = (const float*)d_in[3];
  const float* bk = (const float*)d_in[4];
  const float* Wv = (const float*)d_in[5];
  const float* bv = (const float*)d_in[6];
  // d_in[7] = row_ptr (fixed degree 16) — unused
  const int* col_ind = (const int*)d_in[8];
  // d_in[9] = num_heads (= 8) — hardcoded in layout math

  const int n = in_sizes[0] / HID;  // 50000

  // ws layout (~25.8 MB): k, v bf16 tables + W hi/lo splits. q (bf16) lives in
  // the first 256 B of each row's 512 B fp32 out slot.
  ushort_t* ks  = (ushort_t*)d_ws;
  ushort_t* vs  = ks + (size_t)n * HID;
  ushort_t* whi = vs + (size_t)n * HID;
  ushort_t* wlo = whi + 3 * 16384;
  ushort_t* qs  = (ushort_t*)d_out;
  float* outf   = (float*)d_out;

  prep_kernel<<<24, 256, 0, stream>>>(Wq, Wk, Wv, whi, wlo);
  qkv_fused_kernel<<<(n + 127) / 128, 256, 0, stream>>>(h, bq, bk, bv, whi, wlo, qs, ks, vs, n);
  attn_kernel<<<(n + 3) / 4, 256, 0, stream>>>(col_ind, qs, ks, vs, outf, n);
}

// Round 4
// 173.822 us; speedup vs baseline: 1.1046x; 1.0083x over previous
//
#include <hip/hip_runtime.h>
#include <hip/hip_bf16.h>

// SparseMHA, fixed out-degree CSR graph attention. fp32 in/out.
// r12 -> r13:
//  * attn: r12's coalesced-K-via-LDS was neutral (+1us) -> request-rate theory
//    falsified. Invariants across r9/r10/r12: 179MB FETCH, ~3.9TB/s, ~54us no
//    matter the issue pattern/occupancy => L2-miss-path BYTE-throughput bound.
//    FETCH is 7x the 25.6MB K/V working set because 41.6MB of read-once
//    streaming traffic (q 12.8, col 3.2, out 25.6) cycles through L2 and
//    evicts the K/V rows between their ~3.4us-spaced re-touches. Fix: mark
//    q/col/out accesses NON-TEMPORAL (gfx950 'nt' bit) so only K/V allocate
//    in L2. attn otherwise reverted to the r9 44-VGPR version.
//  * qkv: r9-exact, untouched (r10/r11 proved the schedule is already
//    latency-hidden by 2-blocks/CU overlap; do not touch).

typedef unsigned short ushort_t;
typedef unsigned int uint32;
typedef short short8 __attribute__((ext_vector_type(8)));
typedef short short4v __attribute__((ext_vector_type(4)));
typedef float f32x4 __attribute__((ext_vector_type(4)));
typedef float f32x2 __attribute__((ext_vector_type(2)));

#define HID 128
#define DEG 16
#define OSTRIDE_LDS 132   // ushort row stride in LDS repack (bank-conflict-free)

__device__ __forceinline__ float bf2f(ushort_t u) {
  uint32 x = ((uint32)u) << 16;
  return __builtin_bit_cast(float, x);
}
__device__ __forceinline__ ushort_t f2bf(float f) {
  uint32 u = __builtin_bit_cast(uint32, f);
  u += 0x7fffu + ((u >> 16) & 1u);   // RNE
  return (ushort_t)(u >> 16);
}

// Packed split of 2 fp32 -> packed bf16 hi pair + lo pair (RNE, v_cvt_pk path).
__device__ __forceinline__ void split2(float x, float y, uint32& hi, uint32& lo) {
  __hip_bfloat162 h2 = __float22bfloat162_rn(float2{x, y});
  __builtin_memcpy(&hi, &h2, 4);
  float hx = __builtin_bit_cast(float, hi << 16);
  float hy = __builtin_bit_cast(float, hi & 0xffff0000u);
  __hip_bfloat162 l2 = __float22bfloat162_rn(float2{x - hx, y - hy});
  __builtin_memcpy(&lo, &l2, 4);
}

__device__ __forceinline__ void split8v(float4 a, float4 b, short8& hi, short8& lo) {
  uint32* hu = (uint32*)&hi;
  uint32* lu = (uint32*)&lo;
  split2(a.x, a.y, hu[0], lu[0]);
  split2(a.z, a.w, hu[1], lu[1]);
  split2(b.x, b.y, hu[2], lu[2]);
  split2(b.z, b.w, hu[3], lu[3]);
}

__device__ __forceinline__ void split8p(const float* __restrict__ p, short8& hi, short8& lo) {
  float4 a = *(const float4*)p;
  float4 b = *(const float4*)(p + 4);
  split8v(a, b, hi, lo);
}

// ---------------- Phase 0: pre-split Wq|Wk|Wv into bf16 hi/lo ----------------
__global__ __launch_bounds__(256) void prep_kernel(
    const float* __restrict__ Wq, const float* __restrict__ Wk,
    const float* __restrict__ Wv,
    ushort_t* __restrict__ whi, ushort_t* __restrict__ wlo) {
  const int idx8 = (blockIdx.x * 256 + threadIdx.x) * 8;   // [0, 49152)
  const float* W = (idx8 < 16384) ? Wq : (idx8 < 32768) ? Wk : Wv;
  const int off = idx8 & 16383;
  short8 hi, lo;
  split8p(W + off, hi, lo);
  *(short8*)(whi + idx8) = hi;
  *(short8*)(wlo + idx8) = lo;
}

// ---------------- Phase 1: fused Q+K+V projection (r9-exact) ----------------
// One block = 128 rows (4 waves x 32 rows, 2 A-fragments each). For each of
// the 3 projections: DMA Wh fragments -> LDS (32KB, exact lane order), sync,
// MFMA (ah*bh, al*bh), sync, DMA Wl over same buffer, sync, MFMA (ah*bl),
// sync; then per-wave LDS repack -> coalesced 8B/lane stores.
// B fragment slot j = t*4+kt (1KB each): lane l holds bytes j*1024 + l*16.
__global__ __launch_bounds__(256) void qkv_fused_kernel(
    const float* __restrict__ h,
    const float* __restrict__ bq, const float* __restrict__ bk,
    const float* __restrict__ bv,
    const ushort_t* __restrict__ whi, const ushort_t* __restrict__ wlo,
    ushort_t* __restrict__ qs, ushort_t* __restrict__ ks, ushort_t* __restrict__ vs,
    int n) {
  __shared__ __align__(16) char lds_b[32 * 1024];            // B fragments (reused 6x)
  __shared__ ushort_t lds_r[4][32 * OSTRIDE_LDS];            // repack, 33 KB

  const int wave = threadIdx.x >> 6;
  const int l = threadIdx.x & 63;
  const int lm = l & 15;
  const int lq = l >> 4;
  const int m0 = blockIdx.x * 128 + wave * 32;

  // --- A: load h rows and split to bf16 hi/lo ONCE; reused by all 3 projections.
  int ar0 = m0 + lm;        if (ar0 >= n) ar0 = n - 1;
  int ar1 = m0 + 16 + lm;   if (ar1 >= n) ar1 = n - 1;
  const float* ap0 = h + (size_t)ar0 * HID + lq * 8;
  const float* ap1 = h + (size_t)ar1 * HID + lq * 8;
  short8 ah0[4], al0[4], ah1[4], al1[4];
#pragma unroll
  for (int kt = 0; kt < 4; kt++) {
    split8p(ap0 + kt * 32, ah0[kt], al0[kt]);
    split8p(ap1 + kt * 32, ah1[kt], al1[kt]);
  }

#pragma unroll 1
  for (int p = 0; p < 3; p++) {
    const ushort_t* __restrict__ Wh = whi + p * 16384;
    const ushort_t* __restrict__ Wl = wlo + p * 16384;
    const float* __restrict__ bias = (p == 0) ? bq : (p == 1) ? bk : bv;
    ushort_t* __restrict__ outp = (p == 0) ? qs : (p == 1) ? ks : vs;
    const int ostride = (p == 0) ? 256 : 128;   // q lives inside 512B fp32 out rows
    const float scale = (p == 0) ? 0.25f : 1.0f;

    f32x4 acc[2][8];
#pragma unroll
    for (int f = 0; f < 2; f++)
#pragma unroll
      for (int t = 0; t < 8; t++) acc[f][t] = (f32x4){0.f, 0.f, 0.f, 0.f};

    // ---- hi phase ----
#pragma unroll
    for (int jj = 0; jj < 8; jj++) {            // wave covers j = wave*8 + jj
      const int j = wave * 8 + jj, t = j >> 2, kt = j & 3;
      const ushort_t* gp = Wh + (t * 16 + lm) * HID + kt * 32 + lq * 8;
      __builtin_amdgcn_global_load_lds(
          (const __attribute__((address_space(1))) void*)gp,
          (__attribute__((address_space(3))) void*)(lds_b + j * 1024 + l * 16),
          16, 0, 0);
    }
    __syncthreads();                             // DMA drained for all waves
#pragma unroll
    for (int kt = 0; kt < 4; kt++) {
#pragma unroll
      for (int t = 0; t < 8; t++) {
        short8 bh = *(const short8*)(lds_b + (t * 4 + kt) * 1024 + l * 16);
        acc[0][t] = __builtin_amdgcn_mfma_f32_16x16x32_bf16(ah0[kt], bh, acc[0][t], 0, 0, 0);
        acc[0][t] = __builtin_amdgcn_mfma_f32_16x16x32_bf16(al0[kt], bh, acc[0][t], 0, 0, 0);
        acc[1][t] = __builtin_amdgcn_mfma_f32_16x16x32_bf16(ah1[kt], bh, acc[1][t], 0, 0, 0);
        acc[1][t] = __builtin_amdgcn_mfma_f32_16x16x32_bf16(al1[kt], bh, acc[1][t], 0, 0, 0);
      }
    }
    __syncthreads();                             // all waves done reading hi

    // ---- lo phase (overwrites lds_b) ----
#pragma unroll
    for (int jj = 0; jj < 8; jj++) {
      const int j = wave * 8 + jj, t = j >> 2, kt = j & 3;
      const ushort_t* gp = Wl + (t * 16 + lm) * HID + kt * 32 + lq * 8;
      __builtin_amdgcn_global_load_lds(
          (const __attribute__((address_space(1))) void*)gp,
          (__attribute__((address_space(3))) void*)(lds_b + j * 1024 + l * 16),
          16, 0, 0);
    }
    __syncthreads();
#pragma unroll
    for (int kt = 0; kt < 4; kt++) {
#pragma unroll
      for (int t = 0; t < 8; t++) {
        short8 bl = *(const short8*)(lds_b + (t * 4 + kt) * 1024 + l * 16);
        acc[0][t] = __builtin_amdgcn_mfma_f32_16x16x32_bf16(ah0[kt], bl, acc[0][t], 0, 0, 0);
        acc[1][t] = __builtin_amdgcn_mfma_f32_16x16x32_bf16(ah1[kt], bl, acc[1][t], 0, 0, 0);
      }
    }
    __syncthreads();                             // protect lds_b for next projection

    // ---- epilogue: fragments -> per-wave LDS repack -> coalesced stores ----
    ushort_t* lo_ = lds_r[wave];
#pragma unroll
    for (int t = 0; t < 8; t++) {
      const int col = t * 16 + lm;
      const float bv_ = bias[col];
#pragma unroll
      for (int f = 0; f < 2; f++) {
#pragma unroll
        for (int r = 0; r < 4; r++) {
          lo_[(f * 16 + lq * 4 + r) * OSTRIDE_LDS + col] = f2bf((acc[f][t][r] + bv_) * scale);
        }
      }
    }
    asm volatile("s_waitcnt lgkmcnt(0)" ::: "memory");   // wave-local ordering
    __builtin_amdgcn_wave_barrier();

    const int rr = l >> 5;
    const int ch = l & 31;
#pragma unroll
    for (int it = 0; it < 16; it++) {
      const int rw = it * 2 + rr;                // row within wave, 0..31
      const int grow = m0 + rw;
      short4v val = *(short4v*)(lo_ + rw * OSTRIDE_LDS + ch * 4);
      if (grow < n) *(short4v*)(outp + (size_t)grow * ostride + ch * 4) = val;
    }
  }
}

// ---------------- Phase 2: fused scores + softmax + aggregate ----------------
// One wave per row (r9 structure). Streaming traffic (q, col_ind, out) is
// NON-TEMPORAL so only the K/V tables allocate in L2.
__global__ __launch_bounds__(256) void attn_kernel(
    const int* __restrict__ col_ind,
    const ushort_t* __restrict__ qs, const ushort_t* __restrict__ ks,
    const ushort_t* __restrict__ vs, float* __restrict__ out, int n) {
  __shared__ __align__(16) float lds_attn[4 * DEG * 8];  // [wave][edge][head]

  const int wv = threadIdx.x >> 6;
  const int l = threadIdx.x & 63;
  const int lm = l & 15;
  const int lq = l >> 4;

  int row = blockIdx.x * 4 + wv;
  if (row >= n) row = n - 1;
  const int eb = row * DEG;

  // this lane's A-operand edge (streaming: nt)
  const int cm = __builtin_nontemporal_load(col_ind + eb + lm);
  const ushort_t* kp = ks + (size_t)cm * HID + lq * 8;
  const ushort_t* qp = qs + (size_t)row * 256;     // q embedded in out row

  short8 af[4];
  ushort_t qv[4];
#pragma unroll
  for (int kt = 0; kt < 4; kt++) {
    af[kt] = *(const short8*)(kp + kt * 32);       // K: cached (reused 16x)
    qv[kt] = (lm < 8) ? __builtin_nontemporal_load(qp + kt * 32 + lq * 8 + lm)
                      : (ushort_t)0;               // q: streaming, nt
  }

  uint32 vreg[DEG];
#pragma unroll
  for (int e = 0; e < DEG; e++) {
    const int c = col_ind[eb + e];                 // wave-uniform -> s_load
    vreg[e] = *(const uint32*)(vs + (size_t)c * HID + 2 * l);  // V: cached
  }

  f32x4 acc = (f32x4){0.f, 0.f, 0.f, 0.f};
#pragma unroll
  for (int kt = 0; kt < 4; kt++) {
    short8 bf;
#pragma unroll
    for (int j = 0; j < 8; j++) bf[j] = (lm == j) ? (short)qv[kt] : (short)0;
    acc = __builtin_amdgcn_mfma_f32_16x16x32_bf16(af[kt], bf, acc, 0, 0, 0);
  }

  float m = fmaxf(fmaxf(acc[0], acc[1]), fmaxf(acc[2], acc[3]));
  m = fmaxf(m, __shfl_xor(m, 16, 64));
  m = fmaxf(m, __shfl_xor(m, 32, 64));
  float e0 = __expf(acc[0] - m), e1 = __expf(acc[1] - m);
  float e2 = __expf(acc[2] - m), e3 = __expf(acc[3] - m);
  float s = e0 + e1 + e2 + e3;
  s += __shfl_xor(s, 16, 64);
  s += __shfl_xor(s, 32, 64);
  const float inv = 1.0f / s;

  float* ap = &lds_attn[wv * (DEG * 8)];
  if (lm < 8) {
    ap[(lq * 4 + 0) * 8 + lm] = e0 * inv;
    ap[(lq * 4 + 1) * 8 + lm] = e1 * inv;
    ap[(lq * 4 + 2) * 8 + lm] = e2 * inv;
    ap[(lq * 4 + 3) * 8 + lm] = e3 * inv;
  }
  asm volatile("s_waitcnt lgkmcnt(0)" ::: "memory");
  __builtin_amdgcn_wave_barrier();

  const int h0 = 2 * (l & 3);
  float o0 = 0.f, o1 = 0.f;
#pragma unroll
  for (int e = 0; e < DEG; e++) {
    const float2 at = *(const float2*)(ap + e * 8 + h0);
    o0 += at.x * bf2f((ushort_t)(vreg[e] & 0xffffu));
    o1 += at.y * bf2f((ushort_t)(vreg[e] >> 16));
  }

  f32x2 o;
  o[0] = o0; o[1] = o1;
  // out store: streaming, nt (overwrites consumed q)
  __builtin_nontemporal_store(o, (f32x2*)(out + (size_t)row * HID + 2 * l));
}

extern "C" void kernel_launch(void* const* d_in, const int* in_sizes, int n_in,
                              void* d_out, int out_size, void* d_ws, size_t ws_size,
                              hipStream_t stream) {
  const float* h  = (const float*)d_in[0];
  const float* Wq = (const float*)d_in[1];
  const float* bq = (const float*)d_in[2];
  const float* Wk = (const float*)d_in[3];
  const float* bk = (const float*)d_in[4];
  const float* Wv = (const float*)d_in[5];
  const float* bv = (const float*)d_in[6];
  // d_in[7] = row_ptr (fixed degree 16) — unused
  const int* col_ind = (const int*)d_in[8];
  // d_in[9] = num_heads (= 8) — hardcoded in layout math

  const int n = in_sizes[0] / HID;  // 50000

  // ws layout (~25.8 MB): k, v bf16 tables + W hi/lo splits. q (bf16) lives in
  // the first 256 B of each row's 512 B fp32 out slot.
  ushort_t* ks  = (ushort_t*)d_ws;
  ushort_t* vs  = ks + (size_t)n * HID;
  ushort_t* whi = vs + (size_t)n * HID;
  ushort_t* wlo = whi + 3 * 16384;
  ushort_t* qs  = (ushort_t*)d_out;
  float* outf   = (float*)d_out;

  prep_kernel<<<24, 256, 0, stream>>>(Wq, Wk, Wv, whi, wlo);
  qkv_fused_kernel<<<(n + 127) / 128, 256, 0, stream>>>(h, bq, bk, bv, whi, wlo, qs, ks, vs, n);
  attn_kernel<<<(n + 3) / 4, 256, 0, stream>>>(col_ind, qs, ks, vs, outf, n);
}

// Round 5
// 172.741 us; speedup vs baseline: 1.1115x; 1.0063x over previous
//
#include <hip/hip_runtime.h>
#include <hip/hip_bf16.h>

// SparseMHA, fixed out-degree CSR graph attention. fp32 in/out.
// r13 -> r14:
//  * attn: nt hints were a no-op (FETCH 179.1MB identical) -> pollution theory
//    falsified. Arithmetic: 8 XCDs x ~86% unique-touch of the 25.6MB K/V
//    table = ~177MB COMPULSORY fetch == measured 179MB. L2 retention is
//    already perfect; bytes are at the floor. Remaining hypothesis: the
//    3.87TB/s on the L2-miss<->L3 path is random-BURST inefficiency (2
//    disjoint 256B bursts per edge, 12.8MB apart). Now K and V are
//    INTERLEAVED per node (512B block: K row | V row) so each edge gather is
//    one contiguous 4-line 512B burst; half the random targets, 2x burst
//    length, same bytes, bit-identical numerics. If neutral -> random-gather
//    ceiling reached; attn done at bf16 precision.
//  * qkv: r9-exact schedule; only the k/v output pointers changed for the
//    interleaved layout (ostride now 256 for all three projections).

typedef unsigned short ushort_t;
typedef unsigned int uint32;
typedef short short8 __attribute__((ext_vector_type(8)));
typedef short short4v __attribute__((ext_vector_type(4)));
typedef float f32x4 __attribute__((ext_vector_type(4)));
typedef float f32x2 __attribute__((ext_vector_type(2)));

#define HID 128
#define DEG 16
#define OSTRIDE_LDS 132   // ushort row stride in LDS repack (bank-conflict-free)

__device__ __forceinline__ float bf2f(ushort_t u) {
  uint32 x = ((uint32)u) << 16;
  return __builtin_bit_cast(float, x);
}
__device__ __forceinline__ ushort_t f2bf(float f) {
  uint32 u = __builtin_bit_cast(uint32, f);
  u += 0x7fffu + ((u >> 16) & 1u);   // RNE
  return (ushort_t)(u >> 16);
}

// Packed split of 2 fp32 -> packed bf16 hi pair + lo pair (RNE, v_cvt_pk path).
__device__ __forceinline__ void split2(float x, float y, uint32& hi, uint32& lo) {
  __hip_bfloat162 h2 = __float22bfloat162_rn(float2{x, y});
  __builtin_memcpy(&hi, &h2, 4);
  float hx = __builtin_bit_cast(float, hi << 16);
  float hy = __builtin_bit_cast(float, hi & 0xffff0000u);
  __hip_bfloat162 l2 = __float22bfloat162_rn(float2{x - hx, y - hy});
  __builtin_memcpy(&lo, &l2, 4);
}

__device__ __forceinline__ void split8v(float4 a, float4 b, short8& hi, short8& lo) {
  uint32* hu = (uint32*)&hi;
  uint32* lu = (uint32*)&lo;
  split2(a.x, a.y, hu[0], lu[0]);
  split2(a.z, a.w, hu[1], lu[1]);
  split2(b.x, b.y, hu[2], lu[2]);
  split2(b.z, b.w, hu[3], lu[3]);
}

__device__ __forceinline__ void split8p(const float* __restrict__ p, short8& hi, short8& lo) {
  float4 a = *(const float4*)p;
  float4 b = *(const float4*)(p + 4);
  split8v(a, b, hi, lo);
}

// ---------------- Phase 0: pre-split Wq|Wk|Wv into bf16 hi/lo ----------------
__global__ __launch_bounds__(256) void prep_kernel(
    const float* __restrict__ Wq, const float* __restrict__ Wk,
    const float* __restrict__ Wv,
    ushort_t* __restrict__ whi, ushort_t* __restrict__ wlo) {
  const int idx8 = (blockIdx.x * 256 + threadIdx.x) * 8;   // [0, 49152)
  const float* W = (idx8 < 16384) ? Wq : (idx8 < 32768) ? Wk : Wv;
  const int off = idx8 & 16383;
  short8 hi, lo;
  split8p(W + off, hi, lo);
  *(short8*)(whi + idx8) = hi;
  *(short8*)(wlo + idx8) = lo;
}

// ---------------- Phase 1: fused Q+K+V projection (r9-exact schedule) --------
// One block = 128 rows (4 waves x 32 rows, 2 A-fragments each). For each of
// the 3 projections: DMA Wh fragments -> LDS (32KB, exact lane order), sync,
// MFMA (ah*bh, al*bh), sync, DMA Wl over same buffer, sync, MFMA (ah*bl),
// sync; then per-wave LDS repack -> coalesced 8B/lane stores.
// Outputs: q -> qs (inside 512B fp32 out rows); k -> kvt[row*256 + 0..127];
// v -> kvt[row*256 + 128..255] (512B interleaved K|V block per node).
__global__ __launch_bounds__(256) void qkv_fused_kernel(
    const float* __restrict__ h,
    const float* __restrict__ bq, const float* __restrict__ bk,
    const float* __restrict__ bv,
    const ushort_t* __restrict__ whi, const ushort_t* __restrict__ wlo,
    ushort_t* __restrict__ qs, ushort_t* __restrict__ kvt,
    int n) {
  __shared__ __align__(16) char lds_b[32 * 1024];            // B fragments (reused 6x)
  __shared__ ushort_t lds_r[4][32 * OSTRIDE_LDS];            // repack, 33 KB

  const int wave = threadIdx.x >> 6;
  const int l = threadIdx.x & 63;
  const int lm = l & 15;
  const int lq = l >> 4;
  const int m0 = blockIdx.x * 128 + wave * 32;

  // --- A: load h rows and split to bf16 hi/lo ONCE; reused by all 3 projections.
  int ar0 = m0 + lm;        if (ar0 >= n) ar0 = n - 1;
  int ar1 = m0 + 16 + lm;   if (ar1 >= n) ar1 = n - 1;
  const float* ap0 = h + (size_t)ar0 * HID + lq * 8;
  const float* ap1 = h + (size_t)ar1 * HID + lq * 8;
  short8 ah0[4], al0[4], ah1[4], al1[4];
#pragma unroll
  for (int kt = 0; kt < 4; kt++) {
    split8p(ap0 + kt * 32, ah0[kt], al0[kt]);
    split8p(ap1 + kt * 32, ah1[kt], al1[kt]);
  }

#pragma unroll 1
  for (int p = 0; p < 3; p++) {
    const ushort_t* __restrict__ Wh = whi + p * 16384;
    const ushort_t* __restrict__ Wl = wlo + p * 16384;
    const float* __restrict__ bias = (p == 0) ? bq : (p == 1) ? bk : bv;
    ushort_t* __restrict__ outp = (p == 0) ? qs : (p == 1) ? kvt : kvt + 128;
    const float scale = (p == 0) ? 0.25f : 1.0f;
    // all three outputs live in 512B rows now: ostride = 256 ushorts

    f32x4 acc[2][8];
#pragma unroll
    for (int f = 0; f < 2; f++)
#pragma unroll
      for (int t = 0; t < 8; t++) acc[f][t] = (f32x4){0.f, 0.f, 0.f, 0.f};

    // ---- hi phase ----
#pragma unroll
    for (int jj = 0; jj < 8; jj++) {            // wave covers j = wave*8 + jj
      const int j = wave * 8 + jj, t = j >> 2, kt = j & 3;
      const ushort_t* gp = Wh + (t * 16 + lm) * HID + kt * 32 + lq * 8;
      __builtin_amdgcn_global_load_lds(
          (const __attribute__((address_space(1))) void*)gp,
          (__attribute__((address_space(3))) void*)(lds_b + j * 1024 + l * 16),
          16, 0, 0);
    }
    __syncthreads();                             // DMA drained for all waves
#pragma unroll
    for (int kt = 0; kt < 4; kt++) {
#pragma unroll
      for (int t = 0; t < 8; t++) {
        short8 bh = *(const short8*)(lds_b + (t * 4 + kt) * 1024 + l * 16);
        acc[0][t] = __builtin_amdgcn_mfma_f32_16x16x32_bf16(ah0[kt], bh, acc[0][t], 0, 0, 0);
        acc[0][t] = __builtin_amdgcn_mfma_f32_16x16x32_bf16(al0[kt], bh, acc[0][t], 0, 0, 0);
        acc[1][t] = __builtin_amdgcn_mfma_f32_16x16x32_bf16(ah1[kt], bh, acc[1][t], 0, 0, 0);
        acc[1][t] = __builtin_amdgcn_mfma_f32_16x16x32_bf16(al1[kt], bh, acc[1][t], 0, 0, 0);
      }
    }
    __syncthreads();                             // all waves done reading hi

    // ---- lo phase (overwrites lds_b) ----
#pragma unroll
    for (int jj = 0; jj < 8; jj++) {
      const int j = wave * 8 + jj, t = j >> 2, kt = j & 3;
      const ushort_t* gp = Wl + (t * 16 + lm) * HID + kt * 32 + lq * 8;
      __builtin_amdgcn_global_load_lds(
          (const __attribute__((address_space(1))) void*)gp,
          (__attribute__((address_space(3))) void*)(lds_b + j * 1024 + l * 16),
          16, 0, 0);
    }
    __syncthreads();
#pragma unroll
    for (int kt = 0; kt < 4; kt++) {
#pragma unroll
      for (int t = 0; t < 8; t++) {
        short8 bl = *(const short8*)(lds_b + (t * 4 + kt) * 1024 + l * 16);
        acc[0][t] = __builtin_amdgcn_mfma_f32_16x16x32_bf16(ah0[kt], bl, acc[0][t], 0, 0, 0);
        acc[1][t] = __builtin_amdgcn_mfma_f32_16x16x32_bf16(ah1[kt], bl, acc[1][t], 0, 0, 0);
      }
    }
    __syncthreads();                             // protect lds_b for next projection

    // ---- epilogue: fragments -> per-wave LDS repack -> coalesced stores ----
    ushort_t* lo_ = lds_r[wave];
#pragma unroll
    for (int t = 0; t < 8; t++) {
      const int col = t * 16 + lm;
      const float bv_ = bias[col];
#pragma unroll
      for (int f = 0; f < 2; f++) {
#pragma unroll
        for (int r = 0; r < 4; r++) {
          lo_[(f * 16 + lq * 4 + r) * OSTRIDE_LDS + col] = f2bf((acc[f][t][r] + bv_) * scale);
        }
      }
    }
    asm volatile("s_waitcnt lgkmcnt(0)" ::: "memory");   // wave-local ordering
    __builtin_amdgcn_wave_barrier();

    const int rr = l >> 5;
    const int ch = l & 31;
#pragma unroll
    for (int it = 0; it < 16; it++) {
      const int rw = it * 2 + rr;                // row within wave, 0..31
      const int grow = m0 + rw;
      short4v val = *(short4v*)(lo_ + rw * OSTRIDE_LDS + ch * 4);
      if (grow < n) *(short4v*)(outp + (size_t)grow * 256 + ch * 4) = val;
    }
  }
}

// ---------------- Phase 2: fused scores + softmax + aggregate ----------------
// One wave per row (r9 structure). K|V interleaved per node: one 512B
// contiguous burst per edge instead of two disjoint 256B bursts.
__global__ __launch_bounds__(256) void attn_kernel(
    const int* __restrict__ col_ind,
    const ushort_t* __restrict__ qs, const ushort_t* __restrict__ kvt,
    float* __restrict__ out, int n) {
  __shared__ __align__(16) float lds_attn[4 * DEG * 8];  // [wave][edge][head]

  const int wv = threadIdx.x >> 6;
  const int l = threadIdx.x & 63;
  const int lm = l & 15;
  const int lq = l >> 4;

  int row = blockIdx.x * 4 + wv;
  if (row >= n) row = n - 1;
  const int eb = row * DEG;

  // this lane's A-operand edge (streaming: nt)
  const int cm = __builtin_nontemporal_load(col_ind + eb + lm);
  const ushort_t* kp = kvt + (size_t)cm * 256 + lq * 8;   // K half of node block
  const ushort_t* qp = qs + (size_t)row * 256;     // q embedded in out row

  short8 af[4];
  ushort_t qv[4];
#pragma unroll
  for (int kt = 0; kt < 4; kt++) {
    af[kt] = *(const short8*)(kp + kt * 32);       // K: cached (reused 16x)
    qv[kt] = (lm < 8) ? __builtin_nontemporal_load(qp + kt * 32 + lq * 8 + lm)
                      : (ushort_t)0;               // q: streaming, nt
  }

  uint32 vreg[DEG];
#pragma unroll
  for (int e = 0; e < DEG; e++) {
    const int c = col_ind[eb + e];                 // wave-uniform -> s_load
    vreg[e] = *(const uint32*)(kvt + (size_t)c * 256 + 128 + 2 * l);  // V half
  }

  f32x4 acc = (f32x4){0.f, 0.f, 0.f, 0.f};
#pragma unroll
  for (int kt = 0; kt < 4; kt++) {
    short8 bf;
#pragma unroll
    for (int j = 0; j < 8; j++) bf[j] = (lm == j) ? (short)qv[kt] : (short)0;
    acc = __builtin_amdgcn_mfma_f32_16x16x32_bf16(af[kt], bf, acc, 0, 0, 0);
  }

  float m = fmaxf(fmaxf(acc[0], acc[1]), fmaxf(acc[2], acc[3]));
  m = fmaxf(m, __shfl_xor(m, 16, 64));
  m = fmaxf(m, __shfl_xor(m, 32, 64));
  float e0 = __expf(acc[0] - m), e1 = __expf(acc[1] - m);
  float e2 = __expf(acc[2] - m), e3 = __expf(acc[3] - m);
  float s = e0 + e1 + e2 + e3;
  s += __shfl_xor(s, 16, 64);
  s += __shfl_xor(s, 32, 64);
  const float inv = 1.0f / s;

  float* ap = &lds_attn[wv * (DEG * 8)];
  if (lm < 8) {
    ap[(lq * 4 + 0) * 8 + lm] = e0 * inv;
    ap[(lq * 4 + 1) * 8 + lm] = e1 * inv;
    ap[(lq * 4 + 2) * 8 + lm] = e2 * inv;
    ap[(lq * 4 + 3) * 8 + lm] = e3 * inv;
  }
  asm volatile("s_waitcnt lgkmcnt(0)" ::: "memory");
  __builtin_amdgcn_wave_barrier();

  const int h0 = 2 * (l & 3);
  float o0 = 0.f, o1 = 0.f;
#pragma unroll
  for (int e = 0; e < DEG; e++) {
    const float2 at = *(const float2*)(ap + e * 8 + h0);
    o0 += at.x * bf2f((ushort_t)(vreg[e] & 0xffffu));
    o1 += at.y * bf2f((ushort_t)(vreg[e] >> 16));
  }

  f32x2 o;
  o[0] = o0; o[1] = o1;
  // out store: streaming, nt (overwrites consumed q)
  __builtin_nontemporal_store(o, (f32x2*)(out + (size_t)row * HID + 2 * l));
}

extern "C" void kernel_launch(void* const* d_in, const int* in_sizes, int n_in,
                              void* d_out, int out_size, void* d_ws, size_t ws_size,
                              hipStream_t stream) {
  const float* h  = (const float*)d_in[0];
  const float* Wq = (const float*)d_in[1];
  const float* bq = (const float*)d_in[2];
  const float* Wk = (const float*)d_in[3];
  const float* bk = (const float*)d_in[4];
  const float* Wv = (const float*)d_in[5];
  const float* bv = (const float*)d_in[6];
  // d_in[7] = row_ptr (fixed degree 16) — unused
  const int* col_ind = (const int*)d_in[8];
  // d_in[9] = num_heads (= 8) — hardcoded in layout math

  const int n = in_sizes[0] / HID;  // 50000

  // ws layout (~25.8 MB): interleaved K|V table (512B/node) + W hi/lo splits.
  // q (bf16) lives in the first 256 B of each row's 512 B fp32 out slot.
  ushort_t* kvt = (ushort_t*)d_ws;
  ushort_t* whi = kvt + (size_t)n * 256;
  ushort_t* wlo = whi + 3 * 16384;
  ushort_t* qs  = (ushort_t*)d_out;
  float* outf   = (float*)d_out;

  prep_kernel<<<24, 256, 0, stream>>>(Wq, Wk, Wv, whi, wlo);
  qkv_fused_kernel<<<(n + 127) / 128, 256, 0, stream>>>(h, bq, bk, bv, whi, wlo, qs, kvt, n);
  attn_kernel<<<(n + 3) / 4, 256, 0, stream>>>(col_ind, qs, kvt, outf, n);
}